// Round 11
// baseline (310.333 us; speedup 1.0000x reference)
//
#include <hip/hip_runtime.h>

#define NN 24576
#define DD 32
#define KK 17
#define PP 20
#define WEU ((DD - 1) * PP * KK * KK)   // unpadded W elems per chain

typedef float v2f __attribute__((ext_vector_type(2)));

__device__ __forceinline__ float binom16(int k) {
    const float b[KK] = {1.f, 16.f, 120.f, 560.f, 1820.f, 4368.f, 8008.f, 11440.f,
                         12870.f, 11440.f, 8008.f, 4368.f, 1820.f, 560.f, 120.f, 16.f, 1.f};
    return b[k];
}

// Packed Bernstein: t[k] = x^k * (1-x)^(16-k) for BOTH points at once.
// All indices compile-time (full unroll) -> stays in registers (rule #20).
__device__ __forceinline__ void bernT2(v2f x, v2f* t) {
    const v2f one = {1.0f, 1.0f};
    const v2f y = one - x;
    t[0] = one;
#pragma unroll
    for (int k = 1; k < KK; ++k) t[k] = t[k - 1] * x;
    v2f yp = y;
#pragma unroll
    for (int k = KK - 2; k >= 0; --k) {
        t[k] *= yp;
        yp *= y;
    }
}

// Binom-folded, UNPADDED weight tables (correctness proven R7/R9/R10).
// W stays on the s_load/SGPR path — the only delivery mechanism that keeps
// the FMA block's VGPR budget intact (R4/R6/R7/R8 all died moving W to VGPRs).
__global__ void prep_w_fold(const float* __restrict__ mw, const float* __restrict__ vw,
                            const float* __restrict__ mw0, const float* __restrict__ vw0,
                            const float* __restrict__ psc,
                            float* __restrict__ Wm2, float* __restrict__ Wv2,
                            float* __restrict__ w0m, float* __restrict__ w0v) {
    int idx = blockIdx.x * blockDim.x + threadIdx.x;
    if (idx < WEU) {
        const int j = idx % KK;
        Wm2[idx] = mw[idx] * binom16(j);
    } else if (idx < 2 * WEU) {
        const int i = idx - WEU;
        const int j = i % KK;
        const float s = psc[j] * binom16(j);
        Wv2[i] = expf(vw[i]) * s * s;
    } else if (idx < 2 * WEU + PP * KK) {
        const int i = idx - 2 * WEU;
        const int k = i % KK;
        w0m[i] = mw0[i] * binom16(k);
    } else if (idx < 2 * WEU + 2 * PP * KK) {
        const int i = idx - 2 * WEU - PP * KK;
        const int k = i % KK;
        const float s = psc[k] * binom16(k);
        w0v[i] = expf(vw0[i]) * s * s;
    }
}

// Transpose X [N,D] -> XT [D,N] so chain-kernel loads are lane-coalesced.
__global__ void transpose_x(const float* __restrict__ X, float* __restrict__ XT) {
    __shared__ float t[32][33];
    const int n0 = blockIdx.x * 32;
    for (int r = threadIdx.y; r < 32; r += 8)
        t[r][threadIdx.x] = X[(n0 + r) * DD + threadIdx.x];
    __syncthreads();
    for (int d = threadIdx.y; d < 32; d += 8)
        XT[d * NN + n0 + threadIdx.x] = t[threadIdx.x][d];
}

// R10's proven structure (bern BEFORE FMA block, no setprio, no reordering),
// element type changed to packed <2 x float>: the two n-points ride the lo/hi
// halves of v_pk_fma_f32 / v_pk_mul_f32. W stays a scalar s_load (VOP3P
// op_sel broadcast) -> FMA issue count halves at identical W delivery.
__global__ __launch_bounds__(256, 4) void bez_chainP(
    const float* __restrict__ Xb,       // XT [DD,NN]
    const float* __restrict__ w0m,      // [PP,KK] folded
    const float* __restrict__ mW,       // [DD-1,PP,KK,KK] folded
    const float* __restrict__ w0v,      // [PP,KK] folded
    const float* __restrict__ vW,       // [DD-1,PP,KK,KK] folded
    const float* __restrict__ post_prec,// [PP]
    const int* __restrict__ perm,       // [PP,DD]
    float* __restrict__ out)            // [2*NN]
{
    const bool VAR = (blockIdx.z != 0);          // block-uniform branch
    const int p = blockIdx.y;
    const int n0 = blockIdx.x * 512 + threadIdx.x;
    const int n1 = n0 + 256;
    const int* __restrict__ pp = perm + p * DD;

    const float* __restrict__ w0 = (VAR ? w0v : w0m);
    const float* __restrict__ W  = (VAR ? vW  : mW);

    v2f f[KK], b[KK];

    {
        const int pd = pp[0];
        const v2f x01 = {Xb[pd * NN + n0], Xb[pd * NN + n1]};
        bernT2(x01, b);
        if (VAR) {
#pragma unroll
            for (int k = 0; k < KK; ++k) b[k] *= b[k];
        }
        const float* __restrict__ w0p = w0 + p * KK;
#pragma unroll
        for (int k = 0; k < KK; ++k) f[k] = w0p[k] * b[k];   // scalar*vec -> pk_mul
    }

    for (int d = 1; d < DD; ++d) {
        const int pd = pp[d];
        const v2f x01 = {Xb[pd * NN + n0], Xb[pd * NN + n1]};
        bernT2(x01, b);
        if (VAR) {
#pragma unroll
            for (int k = 0; k < KK; ++k) b[k] *= b[k];
        }

        const float* __restrict__ Wd = W + ((size_t)(d - 1) * PP + p) * (KK * KK);

        v2f fn[KK];
#pragma unroll
        for (int j = 0; j < KK; ++j)                 // k=0 row: init with pk_mul
            fn[j] = f[0] * Wd[j];
#pragma unroll
        for (int k = 1; k < KK; ++k) {
            const v2f fk = f[k];
#pragma unroll
            for (int j = 0; j < KK; ++j) {
                const float w = Wd[k * KK + j];      // uniform -> ONE s_load stream
                const v2f wv = {w, w};
                fn[j] = __builtin_elementwise_fma(fk, wv, fn[j]);   // v_pk_fma_f32
            }
        }
#pragma unroll
        for (int j = 0; j < KK; ++j) f[j] = fn[j] * b[j];   // pk_mul
    }

    v2f s = {0.0f, 0.0f};
#pragma unroll
    for (int j = 0; j < KK; ++j) s += f[j];
    if (VAR) {
        const float ip = 1.0f / post_prec[p];
        s *= ip;
    }

    const int base = VAR ? NN : 0;
    atomicAdd(&out[base + n0], s.x);
    atomicAdd(&out[base + n1], s.y);
}

// ---------- fallback (tiny workspace): round-2 proven path ----------
__device__ __forceinline__ void bern17(float x, float* b) {
    const float y = 1.0f - x;
    b[0] = 1.0f;
#pragma unroll
    for (int k = 1; k < KK; ++k) b[k] = b[k - 1] * x;
    float yp = 1.0f;
#pragma unroll
    for (int k = KK - 1; k >= 0; --k) {
        b[k] = b[k] * yp * binom16(k);
        yp *= y;
    }
}

__global__ void prep_var(const float* __restrict__ varw, const float* __restrict__ varw0,
                         const float* __restrict__ prior_sc,
                         float* __restrict__ wv, float* __restrict__ wv0) {
    const int E1 = (DD - 1) * PP * KK * KK;
    int idx = blockIdx.x * blockDim.x + threadIdx.x;
    if (idx < E1) {
        int j = idx % KK;
        float s = prior_sc[j];
        wv[idx] = expf(varw[idx]) * s * s;
    } else if (idx < E1 + PP * KK) {
        int i = idx - E1;
        int k = i % KK;
        float s = prior_sc[k];
        wv0[i] = expf(varw0[i]) * s * s;
    }
}

__global__ __launch_bounds__(256, 4) void bez_chain2(
    const float* __restrict__ Xb, const int sx_d, const int sx_n,
    const float* __restrict__ mw0, const float* __restrict__ mW,
    const float* __restrict__ vw0, const float* __restrict__ vW,
    const float* __restrict__ post_prec, const int* __restrict__ perm,
    float* __restrict__ out)
{
    const bool VAR = (blockIdx.z != 0);
    const int p = blockIdx.y;
    const int n = blockIdx.x * blockDim.x + threadIdx.x;
    const int* __restrict__ pp = perm + p * DD;
    const float* __restrict__ w0 = (VAR ? vw0 : mw0);
    const float* __restrict__ W  = (VAR ? vW  : mW);

    float f[KK], b[KK];
    {
        const int pd = pp[0];
        const float x = Xb[pd * sx_d + n * sx_n];
        bern17(x, b);
        if (VAR) {
#pragma unroll
            for (int k = 0; k < KK; ++k) b[k] *= b[k];
        }
        const float* __restrict__ w0p = w0 + p * KK;
#pragma unroll
        for (int k = 0; k < KK; ++k) f[k] = w0p[k] * b[k];
    }
    for (int d = 1; d < DD; ++d) {
        const int pd = pp[d];
        const float x = Xb[pd * sx_d + n * sx_n];
        bern17(x, b);
        if (VAR) {
#pragma unroll
            for (int k = 0; k < KK; ++k) b[k] *= b[k];
        }
        const float* __restrict__ Wd = W + ((size_t)(d - 1) * PP + p) * (KK * KK);
        float fn[KK];
#pragma unroll
        for (int j = 0; j < KK; ++j) fn[j] = 0.0f;
#pragma unroll
        for (int k = 0; k < KK; ++k) {
            const float fk = f[k];
#pragma unroll
            for (int j = 0; j < KK; ++j)
                fn[j] = fmaf(fk, Wd[k * KK + j], fn[j]);
        }
#pragma unroll
        for (int j = 0; j < KK; ++j) f[j] = fn[j] * b[j];
    }
    float s = 0.0f;
#pragma unroll
    for (int j = 0; j < KK; ++j) s += f[j];
    if (VAR) s /= post_prec[p];
    atomicAdd(&out[(VAR ? NN : 0) + n], s);
}
// --------------------------------------------------------------------

extern "C" void kernel_launch(void* const* d_in, const int* in_sizes, int n_in,
                              void* d_out, int out_size, void* d_ws, size_t ws_size,
                              hipStream_t stream) {
    const float* X    = (const float*)d_in[0];
    const float* mw0  = (const float*)d_in[1];
    const float* mw   = (const float*)d_in[2];
    const float* vw0  = (const float*)d_in[3];
    const float* vw   = (const float*)d_in[4];
    const float* psc  = (const float*)d_in[5];
    const float* ppr  = (const float*)d_in[6];
    const int*   perm = (const int*)d_in[7];
    float* out = (float*)d_out;

    hipMemsetAsync(d_out, 0, (size_t)out_size * sizeof(float), stream);

    const size_t xt_elems = (size_t)DD * NN;
    const size_t need_main = ((size_t)2 * WEU + 2 * PP * KK + xt_elems) * sizeof(float);

    if (ws_size >= need_main) {
        float* Wm2 = (float*)d_ws;             // [31,PP,17,17] folded
        float* Wv2 = Wm2 + WEU;
        float* w0m = Wv2 + WEU;                // [PP,17]
        float* w0v = w0m + PP * KK;
        float* XT  = w0v + PP * KK;            // [D,N]

        const int E = 2 * WEU + 2 * PP * KK;
        prep_w_fold<<<dim3((E + 255) / 256), dim3(256), 0, stream>>>(mw, vw, mw0, vw0, psc,
                                                                     Wm2, Wv2, w0m, w0v);
        transpose_x<<<dim3(NN / 32), dim3(32, 8), 0, stream>>>(X, XT);

        dim3 grid(NN / 512, PP, 2), blk(256);
        bez_chainP<<<grid, blk, 0, stream>>>(XT, w0m, Wm2, w0v, Wv2, ppr, perm, out);
        return;
    }

    // Fallback: round-2 path.
    const size_t wv_elems  = (size_t)(DD - 1) * PP * KK * KK;
    const size_t wv0_elems = (size_t)PP * KK;
    float* wv_b  = (float*)d_ws;
    float* wv0_b = wv_b + wv_elems;
    float* XT    = wv0_b + wv0_elems;

    const int E = (DD - 1) * PP * KK * KK + PP * KK;
    prep_var<<<dim3((E + 255) / 256), dim3(256), 0, stream>>>(vw, vw0, psc, wv_b, wv0_b);

    const bool use_xt = ((wv_elems + wv0_elems + xt_elems) * sizeof(float) <= ws_size);
    const float* Xb = X;
    int sx_d = 1, sx_n = DD;
    if (use_xt) {
        transpose_x<<<dim3(NN / 32), dim3(32, 8), 0, stream>>>(X, XT);
        Xb = XT; sx_d = NN; sx_n = 1;
    }
    dim3 grid(NN / 256, PP, 2), blk(256);
    bez_chain2<<<grid, blk, 0, stream>>>(Xb, sx_d, sx_n, mw0, mw, wv0_b, wv_b, ppr, perm, out);
}

// Round 12
// 288.416 us; speedup vs baseline: 1.0760x; 1.0760x over previous
//
#include <hip/hip_runtime.h>

#define NN 24576
#define DD 32
#define KK 17
#define PP 20
#define WEU ((DD - 1) * PP * KK * KK)   // unpadded W elems per chain

__device__ __forceinline__ float binom16(int k) {
    const float b[KK] = {1.f, 16.f, 120.f, 560.f, 1820.f, 4368.f, 8008.f, 11440.f,
                         12870.f, 11440.f, 8008.f, 4368.f, 1820.f, 560.f, 120.f, 16.f, 1.f};
    return b[k];
}

// t[k] = x^k * (1-x)^(16-k)   (binom folded into weights by prep_w_fold)
__device__ __forceinline__ void bernT(float x, float* t) {
    const float y = 1.0f - x;
    t[0] = 1.0f;
#pragma unroll
    for (int k = 1; k < KK; ++k) t[k] = t[k - 1] * x;
    float yp = y;
#pragma unroll
    for (int k = KK - 2; k >= 0; --k) {
        t[k] *= yp;
        yp *= y;
    }
}

// Binom-folded, UNPADDED weight tables (correctness proven R7/R9/R10).
// W stays on the s_load/SGPR path — the only delivery mechanism that keeps the
// FMA block's VGPR budget intact (R4/R6/R7/R8 all died moving W into VGPRs).
__global__ void prep_w_fold(const float* __restrict__ mw, const float* __restrict__ vw,
                            const float* __restrict__ mw0, const float* __restrict__ vw0,
                            const float* __restrict__ psc,
                            float* __restrict__ Wm2, float* __restrict__ Wv2,
                            float* __restrict__ w0m, float* __restrict__ w0v) {
    int idx = blockIdx.x * blockDim.x + threadIdx.x;
    if (idx < WEU) {
        const int j = idx % KK;
        Wm2[idx] = mw[idx] * binom16(j);
    } else if (idx < 2 * WEU) {
        const int i = idx - WEU;
        const int j = i % KK;
        const float s = psc[j] * binom16(j);
        Wv2[i] = expf(vw[i]) * s * s;
    } else if (idx < 2 * WEU + PP * KK) {
        const int i = idx - 2 * WEU;
        const int k = i % KK;
        w0m[i] = mw0[i] * binom16(k);
    } else if (idx < 2 * WEU + 2 * PP * KK) {
        const int i = idx - 2 * WEU - PP * KK;
        const int k = i % KK;
        const float s = psc[k] * binom16(k);
        w0v[i] = expf(vw0[i]) * s * s;
    }
}

// Transpose X [N,D] -> XT [D,N] so chain-kernel loads are lane-coalesced.
__global__ void transpose_x(const float* __restrict__ X, float* __restrict__ XT) {
    __shared__ float t[32][33];
    const int n0 = blockIdx.x * 32;
    for (int r = threadIdx.y; r < 32; r += 8)
        t[r][threadIdx.x] = X[(n0 + r) * DD + threadIdx.x];
    __syncthreads();
    for (int d = threadIdx.y; d < 32; d += 8)
        XT[d * NN + n0 + threadIdx.x] = t[threadIdx.x][d];
}

// R5's proven 2pt/thread body, byte-identical structure (bern BEFORE the FMA
// block, no setprio, no reordering — R9 proved both perturb regalloc into
// AGPR shuttling; R11 proved pk-fp32 is half-rate and null-negative). Only
// delta vs R5: weights are binom-folded, so the bern chain is bernT.
// Measured: 289.7 us total, VGPR=64, no spill (R10).
__global__ __launch_bounds__(256, 4) void bez_chain2x2(
    const float* __restrict__ Xb,       // XT [DD,NN]
    const float* __restrict__ w0m,      // [PP,KK] folded
    const float* __restrict__ mW,       // [DD-1,PP,KK,KK] folded
    const float* __restrict__ w0v,      // [PP,KK] folded
    const float* __restrict__ vW,       // [DD-1,PP,KK,KK] folded
    const float* __restrict__ post_prec,// [PP]
    const int* __restrict__ perm,       // [PP,DD]
    float* __restrict__ out)            // [2*NN]
{
    const bool VAR = (blockIdx.z != 0);          // block-uniform branch
    const int p = blockIdx.y;
    const int n0 = blockIdx.x * 512 + threadIdx.x;
    const int n1 = n0 + 256;
    const int* __restrict__ pp = perm + p * DD;

    const float* __restrict__ w0 = (VAR ? w0v : w0m);
    const float* __restrict__ W  = (VAR ? vW  : mW);

    float f0[KK], f1[KK], b0[KK], b1[KK];

    {
        const int pd = pp[0];
        const float x0 = Xb[pd * NN + n0];
        const float x1 = Xb[pd * NN + n1];
        bernT(x0, b0);
        bernT(x1, b1);
        if (VAR) {
#pragma unroll
            for (int k = 0; k < KK; ++k) { b0[k] *= b0[k]; b1[k] *= b1[k]; }
        }
        const float* __restrict__ w0p = w0 + p * KK;
#pragma unroll
        for (int k = 0; k < KK; ++k) { f0[k] = w0p[k] * b0[k]; f1[k] = w0p[k] * b1[k]; }
    }

    for (int d = 1; d < DD; ++d) {
        const int pd = pp[d];
        const float x0 = Xb[pd * NN + n0];
        const float x1 = Xb[pd * NN + n1];
        bernT(x0, b0);
        bernT(x1, b1);
        if (VAR) {
#pragma unroll
            for (int k = 0; k < KK; ++k) { b0[k] *= b0[k]; b1[k] *= b1[k]; }
        }

        const float* __restrict__ Wd = W + ((size_t)(d - 1) * PP + p) * (KK * KK);

        float fn0[KK], fn1[KK];
#pragma unroll
        for (int j = 0; j < KK; ++j) {               // k=0 row: init with mul
            const float w = Wd[j];
            fn0[j] = f0[0] * w;
            fn1[j] = f1[0] * w;
        }
#pragma unroll
        for (int k = 1; k < KK; ++k) {
            const float fk0 = f0[k];
            const float fk1 = f1[k];
#pragma unroll
            for (int j = 0; j < KK; ++j) {
                const float w = Wd[k * KK + j];      // uniform -> ONE s_load stream
                fn0[j] = fmaf(fk0, w, fn0[j]);
                fn1[j] = fmaf(fk1, w, fn1[j]);
            }
        }
#pragma unroll
        for (int j = 0; j < KK; ++j) { f0[j] = fn0[j] * b0[j]; f1[j] = fn1[j] * b1[j]; }
    }

    float s0 = 0.0f, s1 = 0.0f;
#pragma unroll
    for (int j = 0; j < KK; ++j) { s0 += f0[j]; s1 += f1[j]; }
    if (VAR) { const float ip = 1.0f / post_prec[p]; s0 *= ip; s1 *= ip; }

    const int base = VAR ? NN : 0;
    atomicAdd(&out[base + n0], s0);
    atomicAdd(&out[base + n1], s1);
}

// ---------- fallback (tiny workspace): round-2 proven path ----------
__device__ __forceinline__ void bern17(float x, float* b) {
    const float y = 1.0f - x;
    b[0] = 1.0f;
#pragma unroll
    for (int k = 1; k < KK; ++k) b[k] = b[k - 1] * x;
    float yp = 1.0f;
#pragma unroll
    for (int k = KK - 1; k >= 0; --k) {
        b[k] = b[k] * yp * binom16(k);
        yp *= y;
    }
}

__global__ void prep_var(const float* __restrict__ varw, const float* __restrict__ varw0,
                         const float* __restrict__ prior_sc,
                         float* __restrict__ wv, float* __restrict__ wv0) {
    const int E1 = (DD - 1) * PP * KK * KK;
    int idx = blockIdx.x * blockDim.x + threadIdx.x;
    if (idx < E1) {
        int j = idx % KK;
        float s = prior_sc[j];
        wv[idx] = expf(varw[idx]) * s * s;
    } else if (idx < E1 + PP * KK) {
        int i = idx - E1;
        int k = i % KK;
        float s = prior_sc[k];
        wv0[i] = expf(varw0[i]) * s * s;
    }
}

__global__ __launch_bounds__(256, 4) void bez_chain2(
    const float* __restrict__ Xb, const int sx_d, const int sx_n,
    const float* __restrict__ mw0, const float* __restrict__ mW,
    const float* __restrict__ vw0, const float* __restrict__ vW,
    const float* __restrict__ post_prec, const int* __restrict__ perm,
    float* __restrict__ out)
{
    const bool VAR = (blockIdx.z != 0);
    const int p = blockIdx.y;
    const int n = blockIdx.x * blockDim.x + threadIdx.x;
    const int* __restrict__ pp = perm + p * DD;
    const float* __restrict__ w0 = (VAR ? vw0 : mw0);
    const float* __restrict__ W  = (VAR ? vW  : mW);

    float f[KK], b[KK];
    {
        const int pd = pp[0];
        const float x = Xb[pd * sx_d + n * sx_n];
        bern17(x, b);
        if (VAR) {
#pragma unroll
            for (int k = 0; k < KK; ++k) b[k] *= b[k];
        }
        const float* __restrict__ w0p = w0 + p * KK;
#pragma unroll
        for (int k = 0; k < KK; ++k) f[k] = w0p[k] * b[k];
    }
    for (int d = 1; d < DD; ++d) {
        const int pd = pp[d];
        const float x = Xb[pd * sx_d + n * sx_n];
        bern17(x, b);
        if (VAR) {
#pragma unroll
            for (int k = 0; k < KK; ++k) b[k] *= b[k];
        }
        const float* __restrict__ Wd = W + ((size_t)(d - 1) * PP + p) * (KK * KK);
        float fn[KK];
#pragma unroll
        for (int j = 0; j < KK; ++j) fn[j] = 0.0f;
#pragma unroll
        for (int k = 0; k < KK; ++k) {
            const float fk = f[k];
#pragma unroll
            for (int j = 0; j < KK; ++j)
                fn[j] = fmaf(fk, Wd[k * KK + j], fn[j]);
        }
#pragma unroll
        for (int j = 0; j < KK; ++j) f[j] = fn[j] * b[j];
    }
    float s = 0.0f;
#pragma unroll
    for (int j = 0; j < KK; ++j) s += f[j];
    if (VAR) s /= post_prec[p];
    atomicAdd(&out[(VAR ? NN : 0) + n], s);
}
// --------------------------------------------------------------------

extern "C" void kernel_launch(void* const* d_in, const int* in_sizes, int n_in,
                              void* d_out, int out_size, void* d_ws, size_t ws_size,
                              hipStream_t stream) {
    const float* X    = (const float*)d_in[0];
    const float* mw0  = (const float*)d_in[1];
    const float* mw   = (const float*)d_in[2];
    const float* vw0  = (const float*)d_in[3];
    const float* vw   = (const float*)d_in[4];
    const float* psc  = (const float*)d_in[5];
    const float* ppr  = (const float*)d_in[6];
    const int*   perm = (const int*)d_in[7];
    float* out = (float*)d_out;

    hipMemsetAsync(d_out, 0, (size_t)out_size * sizeof(float), stream);

    const size_t xt_elems = (size_t)DD * NN;
    const size_t need_main = ((size_t)2 * WEU + 2 * PP * KK + xt_elems) * sizeof(float);

    if (ws_size >= need_main) {
        float* Wm2 = (float*)d_ws;             // [31,PP,17,17] folded
        float* Wv2 = Wm2 + WEU;
        float* w0m = Wv2 + WEU;                // [PP,17]
        float* w0v = w0m + PP * KK;
        float* XT  = w0v + PP * KK;            // [D,N]

        const int E = 2 * WEU + 2 * PP * KK;
        prep_w_fold<<<dim3((E + 255) / 256), dim3(256), 0, stream>>>(mw, vw, mw0, vw0, psc,
                                                                     Wm2, Wv2, w0m, w0v);
        transpose_x<<<dim3(NN / 32), dim3(32, 8), 0, stream>>>(X, XT);

        dim3 grid(NN / 512, PP, 2), blk(256);
        bez_chain2x2<<<grid, blk, 0, stream>>>(XT, w0m, Wm2, w0v, Wv2, ppr, perm, out);
        return;
    }

    // Fallback: round-2 path.
    const size_t wv_elems  = (size_t)(DD - 1) * PP * KK * KK;
    const size_t wv0_elems = (size_t)PP * KK;
    float* wv_b  = (float*)d_ws;
    float* wv0_b = wv_b + wv_elems;
    float* XT    = wv0_b + wv0_elems;

    const int E = (DD - 1) * PP * KK * KK + PP * KK;
    prep_var<<<dim3((E + 255) / 256), dim3(256), 0, stream>>>(vw, vw0, psc, wv_b, wv0_b);

    const bool use_xt = ((wv_elems + wv0_elems + xt_elems) * sizeof(float) <= ws_size);
    const float* Xb = X;
    int sx_d = 1, sx_n = DD;
    if (use_xt) {
        transpose_x<<<dim3(NN / 32), dim3(32, 8), 0, stream>>>(X, XT);
        Xb = XT; sx_d = NN; sx_n = 1;
    }
    dim3 grid(NN / 256, PP, 2), blk(256);
    bez_chain2<<<grid, blk, 0, stream>>>(Xb, sx_d, sx_n, mw0, mw, wv0_b, wv_b, ppr, perm, out);
}